// Round 1
// baseline (488.205 us; speedup 1.0000x reference)
//
#include <hip/hip_runtime.h>
#include <stdint.h>

#pragma clang fp contract(off)

#define NBOX 8000      // 40*40 + 80*80 boxes total (level sizes fixed by in_sizes)
#define CAP  8192      // padded capacity
#define NMAX 1280      // LDS fast-path limit for valid-box count (E[n]=800, sigma~27)

// ---------------- K1: decode boxes, zero output, compact valid keys ----------------
__global__ __launch_bounds__(256) void k_prep(
    const float* __restrict__ outs0, const float* __restrict__ outs1,
    float* __restrict__ out, unsigned* __restrict__ counter,
    float* __restrict__ rec,                 // 5 arrays of CAP: score,x1,y1,x2,y2
    unsigned long long* __restrict__ keys)
{
    int g = blockIdx.x * blockDim.x + threadIdx.x;
    if (g >= NBOX) return;
    // zero the whole output (harness poisons d_out with 0xAA each launch)
    out[5*g+0]=0.f; out[5*g+1]=0.f; out[5*g+2]=0.f; out[5*g+3]=0.f; out[5*g+4]=0.f;

    const float* src; int local, i, j; float xps, yps; int pp;
    if (g < 1600) { src = outs0; local = g;        i = local/40; j = local - i*40; xps=16.f; yps=12.f; pp=1600; }
    else          { src = outs1; local = g - 1600; i = local/80; j = local - i*80; xps= 8.f; yps= 6.f; pp=6400; }

    float prob = src[local];
    float b1 = src[pp   + local];
    float b2 = src[2*pp + local];
    float b3 = src[3*pp + local];
    float b4 = src[4*pp + local];
    bool m = prob > 0.9f;
    // NOTE: reference applies ROW index i to the x coord (ii[:,None]) and COL index j to y.
    float c1 = m ? (b1*xps + (float)i*xps) : b1;
    float c2 = m ? (b2*yps + (float)j*yps) : b2;
    float c3 = m ? (b3*640.0f) : b3;
    float c4 = m ? (b4*480.0f) : b4;
    // xyxy then round (rintf = round-half-even, matches jnp.round)
    float X1 = rintf(c1);
    float Y1 = rintf(c2);
    float X2 = rintf(c3 + c1);
    float Y2 = rintf(c4 + c2);
    rec[0*CAP+g]=prob; rec[1*CAP+g]=X1; rec[2*CAP+g]=Y1; rec[3*CAP+g]=X2; rec[4*CAP+g]=Y2;
    if (m) {
        unsigned pos = atomicAdd(counter, 1u);
        unsigned u = __float_as_uint(prob);
        u ^= (u & 0x80000000u) ? 0xFFFFFFFFu : 0x80000000u;  // monotone float->uint
        // ascending sort of key == descending score, ascending orig idx (stable argsort)
        keys[pos] = ((unsigned long long)(~u) << 32) | (unsigned)g;
    }
}

// ---------------- K2: single-block bitonic sort of the valid keys ----------------
__global__ __launch_bounds__(1024) void k_sort(
    const unsigned* __restrict__ counter,
    const unsigned long long* __restrict__ keys,
    unsigned* __restrict__ sorted_g)
{
    __shared__ unsigned long long sk[CAP];   // 64 KB
    int n = (int)counter[0]; if (n > NBOX) n = NBOX;
    int m = 2; while (m < n) m <<= 1;
    int tid = threadIdx.x;
    for (int t = tid; t < m; t += 1024) sk[t] = (t < n) ? keys[t] : ~0ULL;
    __syncthreads();
    for (int k = 2; k <= m; k <<= 1) {
        for (int j = k >> 1; j > 0; j >>= 1) {
            for (int t = tid; t < m; t += 1024) {
                int ixj = t ^ j;
                if (ixj > t) {
                    unsigned long long a = sk[t], b = sk[ixj];
                    bool up = ((t & k) == 0);
                    if ((a > b) == up) { sk[t] = b; sk[ixj] = a; }
                }
            }
            __syncthreads();
        }
    }
    for (int t = tid; t < n; t += 1024) sorted_g[t] = (unsigned)(sk[t] & 0xFFFFFFFFu);
}

// ---------------- K3: gather sorted boxes, single-wave greedy NMS, write out ----------------
__global__ __launch_bounds__(1024) void k_nms(
    const unsigned* __restrict__ counter,
    const unsigned* __restrict__ sorted_g,
    const float* __restrict__ rec,
    float* __restrict__ out,
    float* __restrict__ fb)                  // fallback scratch if n > NMAX
{
    __shared__ float sArr[6*NMAX];           // x1,y1,x2,y2,area,score
    __shared__ float kArr[5*NMAX];           // kept list: x1,y1,x2,y2,area
    __shared__ unsigned char sKeep[NMAX];
    int n = (int)counter[0]; if (n > NBOX) n = NBOX;
    int tid = threadIdx.x;

    float *X1,*Y1,*X2,*Y2,*AR,*SC,*KX1,*KY1,*KX2,*KY2,*KAR; unsigned char* KP;
    if (n <= NMAX) {
        X1=sArr; Y1=sArr+NMAX; X2=sArr+2*NMAX; Y2=sArr+3*NMAX; AR=sArr+4*NMAX; SC=sArr+5*NMAX;
        KX1=kArr; KY1=kArr+NMAX; KX2=kArr+2*NMAX; KY2=kArr+3*NMAX; KAR=kArr+4*NMAX;
        KP=sKeep;
    } else {  // correctness fallback (never taken for the fixed test input)
        X1=fb; Y1=fb+CAP; X2=fb+2*CAP; Y2=fb+3*CAP; AR=fb+4*CAP; SC=fb+5*CAP;
        KX1=fb+6*CAP; KY1=fb+7*CAP; KX2=fb+8*CAP; KY2=fb+9*CAP; KAR=fb+10*CAP;
        KP=(unsigned char*)(fb+11*CAP);
    }

    for (int p = tid; p < n; p += 1024) {
        unsigned g = sorted_g[p];
        float x1 = rec[1*CAP+g], y1 = rec[2*CAP+g], x2 = rec[3*CAP+g], y2 = rec[4*CAP+g];
        X1[p]=x1; Y1[p]=y1; X2[p]=x2; Y2[p]=y2;
        AR[p]=(x2-x1)*(y2-y1); SC[p]=rec[0*CAP+g];
        KP[p]=0;
    }
    __syncthreads();

    if (tid < 64) {                          // wave 0 does the serial greedy scan
        int lane = tid;
        int kc = 0;
        for (int base = 0; base < n; base += 64) {
            int b = base + lane;
            bool in = b < n;
            float mx1=0.f,my1=0.f,mx2=0.f,my2=0.f,mar=0.f;
            if (in) { mx1=X1[b]; my1=Y1[b]; mx2=X2[b]; my2=Y2[b]; mar=AR[b]; }
            bool dead = !in;
            // suppression by previously-kept boxes (earlier chunks)
            for (int k = 0; k < kc; ++k) {
                float iw = fminf(mx2, KX2[k]) - fmaxf(mx1, KX1[k]); iw = fmaxf(iw, 0.f);
                float ih = fminf(my2, KY2[k]) - fmaxf(my1, KY1[k]); ih = fmaxf(ih, 0.f);
                float inter = iw*ih;
                float uni = mar + KAR[k] - inter;
                if (uni > 0.f && inter > 0.5f*uni) dead = true;   // exact: ints < 2^24
            }
            // within-chunk greedy: serial steps == kept boxes only (ctz skip)
            unsigned long long scan = __ballot(!dead);
            while (scan) {
                int t = __builtin_ctzll(scan);
                scan &= scan - 1;
                float tx1=__shfl(mx1,t), ty1=__shfl(my1,t), tx2=__shfl(mx2,t),
                      ty2=__shfl(my2,t), tar=__shfl(mar,t);
                if (lane == t) { KX1[kc]=mx1; KY1[kc]=my1; KX2[kc]=mx2; KY2[kc]=my2; KAR[kc]=mar; KP[b]=1; }
                kc++;
                bool kill = false;
                if (!dead && lane > t) {
                    float iw = fminf(mx2,tx2) - fmaxf(mx1,tx1); iw = fmaxf(iw,0.f);
                    float ih = fminf(my2,ty2) - fmaxf(my1,ty1); ih = fmaxf(ih,0.f);
                    float inter = iw*ih;
                    float uni = mar + tar - inter;
                    kill = (uni > 0.f) && (inter > 0.5f*uni);
                }
                dead = dead || kill;
                scan &= ~__ballot(dead);
            }
        }
    }
    __syncthreads();

    for (int p = tid; p < n; p += 1024) {
        if (KP[p]) {
            float x1=X1[p], y1=Y1[p], x2=X2[p], y2=Y2[p];
            out[5*p+0]=SC[p]; out[5*p+1]=x1; out[5*p+2]=y1;
            out[5*p+3]=x2-x1; out[5*p+4]=y2-y1;
        }
    }
}

extern "C" void kernel_launch(void* const* d_in, const int* in_sizes, int n_in,
                              void* d_out, int out_size, void* d_ws, size_t ws_size,
                              hipStream_t stream) {
    const float* outs0 = (const float*)d_in[0];
    const float* outs1 = (const float*)d_in[1];
    float* out = (float*)d_out;
    char* ws = (char*)d_ws;
    unsigned*            counter  = (unsigned*)ws;                          // 64 B
    float*               rec      = (float*)(ws + 64);                      // 5*CAP*4 = 160 KB
    unsigned long long*  keys     = (unsigned long long*)(ws + 64 + 5*CAP*4);        // 64 KB
    unsigned*            sorted_g = (unsigned*)(ws + 64 + 5*CAP*4 + CAP*8);          // 32 KB
    float*               fb       = (float*)(ws + 64 + 5*CAP*4 + CAP*8 + CAP*4);     // ~368 KB

    hipMemsetAsync(counter, 0, 64, stream);   // ws is poisoned 0xAA every launch
    hipLaunchKernelGGL(k_prep, dim3((NBOX+255)/256), dim3(256), 0, stream,
                       outs0, outs1, out, counter, rec, keys);
    hipLaunchKernelGGL(k_sort, dim3(1), dim3(1024), 0, stream, counter, keys, sorted_g);
    hipLaunchKernelGGL(k_nms,  dim3(1), dim3(1024), 0, stream, counter, sorted_g, rec, out, fb);
}

// Round 2
// 200.072 us; speedup vs baseline: 2.4402x; 2.4402x over previous
//
#include <hip/hip_runtime.h>
#include <stdint.h>

#pragma clang fp contract(off)

#define NBOX 8000      // 40*40 + 80*80 boxes
#define CAP  8192
#define NFAST 896      // fast-path cap: W<=14 words, tri mask = 6720 u64 = 52.5 KB LDS
#define WMAX 14

// ---------------- K1: decode boxes, zero output, compact valid ----------------
__global__ __launch_bounds__(256) void k_prep(
    const float* __restrict__ outs0, const float* __restrict__ outs1,
    float* __restrict__ out, unsigned* __restrict__ counter,
    unsigned long long* __restrict__ vkeys,
    float* __restrict__ vsc, float* __restrict__ vx1, float* __restrict__ vy1,
    float* __restrict__ vx2, float* __restrict__ vy2)
{
    int g = blockIdx.x * blockDim.x + threadIdx.x;
    if (g >= NBOX) return;
    out[5*g+0]=0.f; out[5*g+1]=0.f; out[5*g+2]=0.f; out[5*g+3]=0.f; out[5*g+4]=0.f;

    const float* src; int local, i, j; float xps, yps; int pp;
    if (g < 1600) { src = outs0; local = g;        i = local/40; j = local - i*40; xps=16.f; yps=12.f; pp=1600; }
    else          { src = outs1; local = g - 1600; i = local/80; j = local - i*80; xps= 8.f; yps= 6.f; pp=6400; }

    float prob = src[local];
    bool m = prob > 0.9f;
    if (!m) return;
    float b1 = src[pp   + local];
    float b2 = src[2*pp + local];
    float b3 = src[3*pp + local];
    float b4 = src[4*pp + local];
    // reference: ROW index i scales x (ii[:,None]), COL index j scales y
    float c1 = b1*xps + (float)i*xps;
    float c2 = b2*yps + (float)j*yps;
    float c3 = b3*640.0f;
    float c4 = b4*480.0f;
    float X1 = rintf(c1);
    float Y1 = rintf(c2);
    float X2 = rintf(c3 + c1);
    float Y2 = rintf(c4 + c2);
    unsigned pos = atomicAdd(counter, 1u);
    unsigned u = __float_as_uint(prob);
    u ^= (u & 0x80000000u) ? 0xFFFFFFFFu : 0x80000000u;   // monotone float->uint
    vkeys[pos] = ((unsigned long long)(~u) << 32) | (unsigned)g;  // asc key = desc score, asc idx
    vsc[pos]=prob; vx1[pos]=X1; vy1[pos]=Y1; vx2[pos]=X2; vy2[pos]=Y2;
}

// ---------------- K2: parallel rank-by-count + scatter into sorted SoA ----------------
__global__ __launch_bounds__(256) void k_rank(
    const unsigned* __restrict__ counter,
    const unsigned long long* __restrict__ vkeys,
    const float* __restrict__ vsc, const float* __restrict__ vx1, const float* __restrict__ vy1,
    const float* __restrict__ vx2, const float* __restrict__ vy2,
    float* __restrict__ ssc, float* __restrict__ sx1, float* __restrict__ sy1,
    float* __restrict__ sx2, float* __restrict__ sy2, float* __restrict__ sar)
{
    int n = (int)counter[0]; if (n > NBOX) n = NBOX;
    int p = blockIdx.x * blockDim.x + threadIdx.x;
    if (p >= n) return;
    unsigned long long kp = vkeys[p];
    int rank = 0;
    for (int q = 0; q < n; ++q) rank += (vkeys[q] < kp) ? 1 : 0;
    float x1 = vx1[p], y1 = vy1[p], x2 = vx2[p], y2 = vy2[p];
    ssc[rank] = vsc[p]; sx1[rank] = x1; sy1[rank] = y1; sx2[rank] = x2; sy2[rank] = y2;
    sar[rank] = (x2 - x1) * (y2 - y1);
}

// ---------------- K3: parallel triangular suppression bit-matrix ----------------
// word (r, w) covers cols [64w, 64w+64); only w >= r/64 stored (cols > r matter).
__global__ __launch_bounds__(256) void k_mask(
    const unsigned* __restrict__ counter,
    const float* __restrict__ sx1, const float* __restrict__ sy1,
    const float* __restrict__ sx2, const float* __restrict__ sy2,
    const float* __restrict__ sar,
    unsigned long long* __restrict__ tri)
{
    int n = (int)counter[0];
    if (n <= 0 || n > NFAST) return;          // fallback path doesn't use the mask
    int W = (n + 63) >> 6;
    int t = blockIdx.x * blockDim.x + threadIdx.x;
    int r = t / WMAX, k = t % WMAX;
    if (r >= n) return;
    int a = r >> 6, b = r & 63;
    int w = a + k;
    if (w >= W) return;
    float rx1 = sx1[r], ry1 = sy1[r], rx2 = sx2[r], ry2 = sy2[r], rar = sar[r];
    unsigned long long word = 0;
    int c0 = w << 6;
    for (int bit = 0; bit < 64; ++bit) {
        int c = c0 + bit;
        if (c >= n) break;
        float iw = fminf(rx2, sx2[c]) - fmaxf(rx1, sx1[c]); iw = fmaxf(iw, 0.f);
        float ih = fminf(ry2, sy2[c]) - fmaxf(ry1, sy1[c]); ih = fmaxf(ih, 0.f);
        float inter = iw * ih;
        float uni = rar + sar[c] - inter;
        if (uni > 0.f && inter > 0.5f * uni)  // exact: rounded ints < 2^24
            word |= 1ULL << bit;
    }
    if (w == a) {  // diagonal word: clear cols c <= r
        unsigned long long low = (b == 63) ? ~0ULL : ((1ULL << (b + 1)) - 1);
        word &= ~low;
    }
    // triangular offset: off(r) = 64*(a*W - a*(a-1)/2) + b*(W-a)
    long long off = 64LL * ((long long)a * W - ((long long)a * (a - 1)) / 2)
                  + (long long)b * (W - a) + (w - a);
    tri[off] = word;
}

// ---------------- K4: LDS greedy scan over bitmask + write kept rows ----------------
__global__ __launch_bounds__(1024) void k_nms2(
    const unsigned* __restrict__ counter,
    const unsigned long long* __restrict__ tri,
    const float* __restrict__ ssc, const float* __restrict__ sx1, const float* __restrict__ sy1,
    const float* __restrict__ sx2, const float* __restrict__ sy2, const float* __restrict__ sar,
    int* __restrict__ kf)
{
    __shared__ unsigned long long ldsTri[6720];   // 52.5 KB (n<=896, W<=14)
    __shared__ unsigned long long keptWords[16];
    int n = (int)counter[0]; if (n > NBOX) n = NBOX;
    if (n <= 0) return;
    int tid = threadIdx.x;

    if (n <= NFAST) {
        int W = (n + 63) >> 6;
        int A = n >> 6, B = n & 63;
        int total = 64 * (A * W - (A * (A - 1)) / 2) + B * (W - A);
        for (int t = tid; t < total; t += 1024) ldsTri[t] = tri[t];
        if (tid < 16) keptWords[tid] = 0;
        __syncthreads();

        if (tid < 64) {
            int lane = tid;
            unsigned long long alive = 0;
            if (lane < W) {
                int cnt = n - (lane << 6);
                alive = (cnt >= 64) ? ~0ULL : ((1ULL << cnt) - 1);
            }
            unsigned long long kept = 0;
            while (true) {
                unsigned long long bal = __ballot(alive != 0);
                if (!bal) break;
                int fl = (int)__builtin_ctzll(bal);
                unsigned long long wsel = __shfl(alive, fl);
                int i = (fl << 6) + (int)__builtin_ctzll(wsel);
                if (lane == fl) {
                    kept  |=  1ULL << (i & 63);
                    alive &= ~(1ULL << (i & 63));
                }
                int a = i >> 6, b = i & 63;
                long long off = 64LL * ((long long)a * W - ((long long)a * (a - 1)) / 2)
                              + (long long)b * (W - a);
                if (lane >= a && lane < W) {
                    unsigned long long rw = ldsTri[off + (lane - a)];
                    alive &= ~rw;   // row only has bits for c > i
                }
            }
            if (lane < W) keptWords[lane] = kept;
        }
        __syncthreads();

        for (int p = tid; p < n; p += 1024) {
            if ((keptWords[p >> 6] >> (p & 63)) & 1ULL) {
                float x1 = sx1[p], y1 = sy1[p], x2 = sx2[p], y2 = sy2[p];
                out_row: ;
                // write row p
                // (out pointer passed via kf trick? no — see below: out passed separately)
            }
        }
    }
}

// NOTE: k_nms2 above needs the out pointer; real definition follows (the stub above
// is replaced — see k_nms3). Kept minimal to avoid divergence: actual kernel below.

__global__ __launch_bounds__(1024) void k_nms3(
    const unsigned* __restrict__ counter,
    const unsigned long long* __restrict__ tri,
    const float* __restrict__ ssc, const float* __restrict__ sx1, const float* __restrict__ sy1,
    const float* __restrict__ sx2, const float* __restrict__ sy2, const float* __restrict__ sar,
    float* __restrict__ out, int* kf_)
{
    __shared__ unsigned long long ldsTri[6720];   // 52.5 KB
    __shared__ unsigned long long keptWords[16];
    int n = (int)counter[0]; if (n > NBOX) n = NBOX;
    if (n <= 0) return;
    int tid = threadIdx.x;

    if (n <= NFAST) {
        int W = (n + 63) >> 6;
        int A = n >> 6, B = n & 63;
        int total = 64 * (A * W - (A * (A - 1)) / 2) + B * (W - A);
        for (int t = tid; t < total; t += 1024) ldsTri[t] = tri[t];
        if (tid < 16) keptWords[tid] = 0;
        __syncthreads();

        if (tid < 64) {
            int lane = tid;
            unsigned long long alive = 0;
            if (lane < W) {
                int cnt = n - (lane << 6);
                alive = (cnt >= 64) ? ~0ULL : ((1ULL << cnt) - 1);
            }
            unsigned long long kept = 0;
            while (true) {
                unsigned long long bal = __ballot(alive != 0);
                if (!bal) break;
                int fl = (int)__builtin_ctzll(bal);
                unsigned long long wsel = __shfl(alive, fl);
                int i = (fl << 6) + (int)__builtin_ctzll(wsel);
                if (lane == fl) {
                    kept  |=  1ULL << (i & 63);
                    alive &= ~(1ULL << (i & 63));
                }
                int a = i >> 6, b = i & 63;
                long long off = 64LL * ((long long)a * W - ((long long)a * (a - 1)) / 2)
                              + (long long)b * (W - a);
                if (lane >= a && lane < W) {
                    unsigned long long rw = ldsTri[off + (lane - a)];
                    alive &= ~rw;
                }
            }
            if (lane < W) keptWords[lane] = kept;
        }
        __syncthreads();

        for (int p = tid; p < n; p += 1024) {
            if ((keptWords[p >> 6] >> (p & 63)) & 1ULL) {
                float x1 = sx1[p], y1 = sy1[p], x2 = sx2[p], y2 = sy2[p];
                out[5*p+0] = ssc[p];
                out[5*p+1] = x1;
                out[5*p+2] = y1;
                out[5*p+3] = x2 - x1;
                out[5*p+4] = y2 - y1;
            }
        }
    } else {
        // -------- correctness-only fallback (n > NFAST): volatile greedy --------
        volatile int* kf = (volatile int*)kf_;
        for (int p = tid; p < n; p += 1024) kf[p] = 1;
        __syncthreads();
        if (tid < 64) {
            int lane = tid;
            for (int i = 0; i < n; ++i) {
                int alive = kf[i];
                if (!alive) continue;
                float ix1 = sx1[i], iy1 = sy1[i], ix2 = sx2[i], iy2 = sy2[i], iar = sar[i];
                for (int j = i + 1 + lane; j < n; j += 64) {
                    float iw = fminf(ix2, sx2[j]) - fmaxf(ix1, sx1[j]); iw = fmaxf(iw, 0.f);
                    float ih = fminf(iy2, sy2[j]) - fmaxf(iy1, sy1[j]); ih = fmaxf(ih, 0.f);
                    float inter = iw * ih;
                    float uni = iar + sar[j] - inter;
                    if (uni > 0.f && inter > 0.5f * uni) kf[j] = 0;
                }
            }
        }
        __threadfence();
        __syncthreads();
        for (int p = tid; p < n; p += 1024) {
            if (kf[p]) {
                float x1 = sx1[p], y1 = sy1[p], x2 = sx2[p], y2 = sy2[p];
                out[5*p+0] = ssc[p];
                out[5*p+1] = x1;
                out[5*p+2] = y1;
                out[5*p+3] = x2 - x1;
                out[5*p+4] = y2 - y1;
            }
        }
    }
}

extern "C" void kernel_launch(void* const* d_in, const int* in_sizes, int n_in,
                              void* d_out, int out_size, void* d_ws, size_t ws_size,
                              hipStream_t stream) {
    const float* outs0 = (const float*)d_in[0];
    const float* outs1 = (const float*)d_in[1];
    float* out = (float*)d_out;
    char* ws = (char*)d_ws;
    size_t o = 0;
    unsigned* counter = (unsigned*)(ws + o);            o += 64;
    unsigned long long* vkeys = (unsigned long long*)(ws + o); o += (size_t)CAP * 8;
    float* vsc = (float*)(ws + o); o += (size_t)CAP * 4;
    float* vx1 = (float*)(ws + o); o += (size_t)CAP * 4;
    float* vy1 = (float*)(ws + o); o += (size_t)CAP * 4;
    float* vx2 = (float*)(ws + o); o += (size_t)CAP * 4;
    float* vy2 = (float*)(ws + o); o += (size_t)CAP * 4;
    float* ssc = (float*)(ws + o); o += (size_t)CAP * 4;
    float* sx1 = (float*)(ws + o); o += (size_t)CAP * 4;
    float* sy1 = (float*)(ws + o); o += (size_t)CAP * 4;
    float* sx2 = (float*)(ws + o); o += (size_t)CAP * 4;
    float* sy2 = (float*)(ws + o); o += (size_t)CAP * 4;
    float* sar = (float*)(ws + o); o += (size_t)CAP * 4;
    unsigned long long* tri = (unsigned long long*)(ws + o); o += 6720ull * 8;
    int* kf = (int*)(ws + o); o += (size_t)CAP * 4;

    hipMemsetAsync(counter, 0, 64, stream);
    hipLaunchKernelGGL(k_prep, dim3((NBOX + 255) / 256), dim3(256), 0, stream,
                       outs0, outs1, out, counter, vkeys, vsc, vx1, vy1, vx2, vy2);
    hipLaunchKernelGGL(k_rank, dim3((NBOX + 255) / 256), dim3(256), 0, stream,
                       counter, vkeys, vsc, vx1, vy1, vx2, vy2,
                       ssc, sx1, sy1, sx2, sy2, sar);
    hipLaunchKernelGGL(k_mask, dim3((NFAST * WMAX + 255) / 256), dim3(256), 0, stream,
                       counter, sx1, sy1, sx2, sy2, sar, tri);
    hipLaunchKernelGGL(k_nms3, dim3(1), dim3(1024), 0, stream,
                       counter, tri, ssc, sx1, sy1, sx2, sy2, sar, out, kf);
}